// Round 6
// baseline (269.304 us; speedup 1.0000x reference)
//
#include <hip/hip_runtime.h>

// Tree-LSTM AST encoder, complete 8-ary tree, N=100000, D=128, C=8.
// Internal nodes 0..12499, leaves 12500..99999 (result == emb row), sentinel 100000.
// Levels (deepest first): L5 [4681,12500) 245x32-tiles | L4 [585,4681) 128 | L3 [73,585) 16
//                         tail (block 0, sequential): L2 [9,73) 2 tiles | L1 [1,9) | root 0.
//
// SINGLE persistent kernel, 256 blocks x 512 threads (1 block/CU, all co-resident),
// device-scope grid barriers between levels (threadfence + agent atomics; the
// documented cross-XCD mechanism). bar_init zeroes barrier state each call
// (ws is poisoned 0xAA after the correctness call). 2 dispatches total.
//
// Per block: 8 waves; wave w owns dims w*16..w*16+15 for all 4 gates; LSTM cell
// fully in registers from MFMA C/D frags (col=lane&15, row=(lane>>4)*4+reg).
// Weights: 32 B-frags (128 regs)/wave from pre-packed f16 wfrag, loaded ONCE for
// all phases. Double-buffered Xh, one intra-block barrier per step, 2-step
// register prefetch of child inputs, f16 results + f16 emb table.
//
// ws: resultsH f16[12500*128] | wfrag f16[131072] | bias4 float4[128]
//     | embH f16[131*128] | bar unsigned[16]

#define D 128
#define NTOT 100000
#define NINT 12500
#define NTYPES 131
#define NB 256

typedef _Float16 f16x8 __attribute__((ext_vector_type(8)));
typedef float    f32x4 __attribute__((ext_vector_type(4)));

__device__ __forceinline__ float fsig(float x) {
    return __builtin_amdgcn_rcpf(1.f + __expf(-x));
}
__device__ __forceinline__ float ftanh(float x) {
    return 1.f - 2.f * __builtin_amdgcn_rcpf(__expf(2.f * x) + 1.f);
}

__global__ void bar_init(unsigned* __restrict__ bar) {
    if (threadIdx.x < 16) bar[threadIdx.x] = 0u;
}

__global__ __launch_bounds__(512) void tree_lstm(
    const float* __restrict__ W_ih, const float* __restrict__ W_hh,
    const float* __restrict__ b_ih, const float* __restrict__ b_hh,
    const float* __restrict__ emb, const int* __restrict__ node_types,
    const int* __restrict__ children,
    _Float16* __restrict__ resultsH, _Float16* __restrict__ wfrag,
    float4* __restrict__ bias4, _Float16* __restrict__ embH,
    unsigned* __restrict__ bar, float* __restrict__ out)
{
    __shared__ __align__(16) _Float16 Xh[2][32][264];   // [buf][node][ x(128)|h(128)|pad ]
    __shared__ int chid_s[32][8];
    __shared__ int chty_s[32][8];
    __shared__ __align__(16) _Float16 Hstash[8][128];

    const int t   = threadIdx.x;
    const int w   = t >> 6;
    const int l   = t & 63;
    const int bid = blockIdx.x;
    const int row = t >> 4;            // gather row (TPR=16)
    const int di  = (t & 15) * 8;      // gather dim offset (DPT=8)
    const int dcol = w * 16 + (l & 15);

    unsigned* cnt  = bar;
    unsigned* flag = bar + 8;

    auto gbar = [&](int slot) {
        __syncthreads();
        if (t == 0) {
            __threadfence();   // agent-scope release of this block's stores
            unsigned old = __hip_atomic_fetch_add(&cnt[slot], 1u,
                                __ATOMIC_ACQ_REL, __HIP_MEMORY_SCOPE_AGENT);
            if (old == NB - 1) {
                __hip_atomic_store(&flag[slot], 1u,
                                   __ATOMIC_RELEASE, __HIP_MEMORY_SCOPE_AGENT);
            } else {
                while (__hip_atomic_load(&flag[slot],
                           __ATOMIC_ACQUIRE, __HIP_MEMORY_SCOPE_AGENT) == 0u)
                    __builtin_amdgcn_s_sleep(2);
            }
        }
        __syncthreads();
    };

    // ================= phase 0: prep (wfrag, bias4, embH) =================
    {
        const int tg = bid * 512 + t;
        if (tg < 8 * 4 * 8 * 64) {     // 16384 B-fragments
            int ll = tg & 63, kk = (tg >> 6) & 7, ct = (tg >> 9) & 3, ww = (tg >> 11) & 7;
            int k0 = (kk & 3) * 32 + ((ll >> 4) * 8);
            int c  = ct * 128 + ww * 16 + (ll & 15);
            const float* src = (kk < 4) ? (W_ih + (size_t)c * D + k0)
                                        : (W_hh + (size_t)c * D + k0);
            f16x8 v;
#pragma unroll
            for (int j = 0; j < 8; ++j) v[j] = (_Float16)src[j];
            *(f16x8*)(wfrag + (size_t)tg * 8) = v;
        }
        if (tg < D)
            bias4[tg] = make_float4(b_ih[tg      ] + b_hh[tg      ],
                                    b_ih[tg + 128] + b_hh[tg + 128],
                                    b_ih[tg + 256] + b_hh[tg + 256],
                                    b_ih[tg + 384] + b_hh[tg + 384]);
        if (tg < NTYPES * D / 8) {     // 2096 chunks
            f16x8 v;
#pragma unroll
            for (int j = 0; j < 8; ++j) v[j] = (_Float16)emb[tg * 8 + j];
            *(f16x8*)(embH + (size_t)tg * 8) = v;
        }
    }
    gbar(0);

    // ======== weights: loaded ONCE, register-resident for all phases ========
    f16x8 bf[4][8];
#pragma unroll
    for (int ct = 0; ct < 4; ++ct)
#pragma unroll
        for (int kk = 0; kk < 8; ++kk)
            bf[ct][kk] = *(const f16x8*)(wfrag + ((size_t)(((w * 4 + ct) * 8 + kk) * 64 + l)) * 8);
    const float4 bb = bias4[dcol];

    float cr[2][4], hr[2][4];
    f32x4 acc[2][4];

    auto mfma_phase = [&](int b) {
#pragma unroll
        for (int rt = 0; rt < 2; ++rt)
#pragma unroll
            for (int ct = 0; ct < 4; ++ct) acc[rt][ct] = (f32x4){0.f, 0.f, 0.f, 0.f};
#pragma unroll
        for (int kk = 0; kk < 8; ++kk) {
#pragma unroll
            for (int rt = 0; rt < 2; ++rt) {
                f16x8 a = *(const f16x8*)&Xh[b][rt * 16 + (l & 15)][kk * 32 + ((l >> 4) * 8)];
#pragma unroll
                for (int ct = 0; ct < 4; ++ct)
                    acc[rt][ct] = __builtin_amdgcn_mfma_f32_16x16x32_f16(a, bf[ct][kk], acc[rt][ct], 0, 0, 0);
            }
        }
    };
    auto cell_phase = [&](int s, int b, bool always) {
#pragma unroll
        for (int rt = 0; rt < 2; ++rt)
#pragma unroll
            for (int r = 0; r < 4; ++r) {
                const int r2 = rt * 16 + ((l >> 4) * 4) + r;
                const bool upd = always || (s == 0) || (chid_s[r2][s - 1] < NTOT);
                if (upd) {
                    float iv = fsig (acc[rt][0][r] + bb.x);
                    float fv = fsig (acc[rt][1][r] + bb.y);
                    float gv = ftanh(acc[rt][2][r] + bb.z);
                    float ov = fsig (acc[rt][3][r] + bb.w);
                    float cn = fv * cr[rt][r] + iv * gv;
                    cr[rt][r] = cn;
                    hr[rt][r] = ov * ftanh(cn);
                }
                if (s < 8) Xh[b ^ 1][r2][128 + dcol] = (_Float16)hr[rt][r];
            }
    };

    auto do_tile = [&](int start, int count, int tile, bool stash) {
        const int n0 = start + tile * 32;
        const int B  = min(32, start + count - n0);

        if (t < 256) {
            int rr = t >> 3, slot = t & 7;
            int ch = children[(size_t)(n0 + rr) * 8 + slot];
            chid_s[rr][slot] = ch;
            chty_s[rr][slot] = (ch >= NINT && ch < NTOT) ? node_types[ch] : 0;
        }
        __syncthreads();

        auto issue_gather = [&](int s) -> f16x8 {
            const _Float16* src;
            if (s == 0) {
                src = embH + (size_t)node_types[n0 + row] * D + di;
            } else {
                int ch = chid_s[row][s - 1];
                if (ch >= NTOT) return (f16x8)(_Float16)0.f;
                src = (ch < NINT) ? (resultsH + (size_t)ch * D + di)
                                  : (embH + (size_t)chty_s[row][s - 1] * D + di);
            }
            return *(const f16x8*)src;
        };

        *(f16x8*)&Xh[0][row][di]       = issue_gather(0);
        *(f16x8*)&Xh[0][row][128 + di] = (f16x8)(_Float16)0.f;
        f16x8 xA = issue_gather(1);
        f16x8 xB = issue_gather(2);
#pragma unroll
        for (int rt = 0; rt < 2; ++rt)
#pragma unroll
            for (int r = 0; r < 4; ++r) { cr[rt][r] = 0.f; hr[rt][r] = 0.f; }
        __syncthreads();

        for (int s = 0; s < 9; ++s) {
            const int b = s & 1;
            mfma_phase(b);
            if (s < 8) {
                *(f16x8*)&Xh[b ^ 1][row][di] = xA;
                xA = xB;
                if (s <= 5) xB = issue_gather(s + 3);
            }
            cell_phase(s, b, false);
            __syncthreads();
        }

#pragma unroll
        for (int rt = 0; rt < 2; ++rt)
#pragma unroll
            for (int r = 0; r < 4; ++r) {
                const int r2 = rt * 16 + ((l >> 4) * 4) + r;
                if (r2 < B) {
                    resultsH[(size_t)(n0 + r2) * D + dcol] = (_Float16)hr[rt][r];
                    if (stash && r2 < 8) Hstash[r2][dcol] = (_Float16)hr[rt][r];
                }
            }
    };

    // ================= levels =================
    if (bid < 245) do_tile(4681, 7819, bid, false);   // L5
    gbar(1);
    if (bid < 128) do_tile(585, 4096, bid, false);    // L4
    gbar(2);
    if (bid < 16)  do_tile(73, 512, bid, false);      // L3
    gbar(3);

    // ========== tail: block 0 runs L2 (2 tiles) + L1 + root sequentially ==========
    if (bid == 0) {
        do_tile(9, 64, 0, false);
        do_tile(9, 64, 1, false);
        do_tile(1, 8, 0, true);     // L1: nodes 1..8 -> Hstash

        // root pass: node 0, children = nodes 1..8 (Hstash)
        __syncthreads();
        *(f16x8*)&Xh[0][row][di]       = *(const f16x8*)(embH + (size_t)node_types[0] * D + di);
        *(f16x8*)&Xh[0][row][128 + di] = (f16x8)(_Float16)0.f;
#pragma unroll
        for (int rt = 0; rt < 2; ++rt)
#pragma unroll
            for (int r = 0; r < 4; ++r) { cr[rt][r] = 0.f; hr[rt][r] = 0.f; }
        __syncthreads();

        for (int s = 0; s < 9; ++s) {
            const int b = s & 1;
            mfma_phase(b);
            if (s < 8)
                *(f16x8*)&Xh[b ^ 1][row][di] = *(const f16x8*)&Hstash[s][di];
            cell_phase(s, b, true);
            __syncthreads();
        }
        if ((l >> 4) == 0) out[dcol] = hr[0][0];
    }
}

extern "C" void kernel_launch(void* const* d_in, const int* in_sizes, int n_in,
                              void* d_out, int out_size, void* d_ws, size_t ws_size,
                              hipStream_t stream)
{
    const float* emb        = (const float*)d_in[0];
    const float* W_ih       = (const float*)d_in[1];
    const float* W_hh       = (const float*)d_in[2];
    const float* b_ih       = (const float*)d_in[3];
    const float* b_hh       = (const float*)d_in[4];
    const int*   node_types = (const int*)d_in[5];
    const int*   children   = (const int*)d_in[6];

    float* out = (float*)d_out;

    char*      ws       = (char*)d_ws;
    _Float16*  resultsH = (_Float16*)ws;                         // 3,200,000 B
    size_t     off      = ((size_t)NINT * D * 2 + 255) & ~(size_t)255;
    _Float16*  wfrag    = (_Float16*)(ws + off);                 // 262,144 B
    float4*    bias4    = (float4*)(ws + off + 262144);          // 2,048 B
    _Float16*  embH     = (_Float16*)(ws + off + 262144 + 2048); // 33,536 B
    unsigned*  barp     = (unsigned*)(ws + off + 262144 + 2048 + 33536); // 64 B

    bar_init<<<1, 64, 0, stream>>>(barp);
    tree_lstm<<<NB, 512, 0, stream>>>(W_ih, W_hh, b_ih, b_hh, emb, node_types, children,
                                      resultsH, wfrag, bias4, embH, barp, out);
}

// Round 7
// 109.400 us; speedup vs baseline: 2.4616x; 2.4616x over previous
//
#include <hip/hip_runtime.h>

// Tree-LSTM AST encoder, complete 8-ary tree, N=100000, D=128, C=8.
// Internal nodes 0..12499, leaves 12500..99999 (result == emb row), sentinel 100000.
// Levels (deepest first): L5 [4681,12500) | L4 [585,4681) | L3 [73,585)
//                         L2 [9,73) | L1 [1,9) | L0 [0,1)  -- L1+L0 fused (1 block).
//
// R6 lesson: with the MFMA *builtin*, the allocator capped at 128 VGPRs and
// REMATERIALIZED the 32 weight B-fragments from L2 inside every mfma phase
// (VGPR=128, no spill traffic, MfmaUtil 3%) -> latency-bound. Fix: inline-asm
// MFMA with an "a" (AGPR) constraint on the B operand. The 32 fragments are
// pinned in 128 AGPRs for the kernel lifetime (gfx950 unified file: ~100 arch
// VGPR + 128 AGPR = ~230 <= 256 @ 2 waves/SIMD) - the compiler cannot remat
// or spill an asm register operand.
//
// Structure = R5 (known good): 8-wave blocks, wave w owns dims w*16..+15 for
// all 4 gates; cell fully in registers from MFMA C/D frags (col=lane&15,
// row=(lane>>4)*4+reg). Double-buffered Xh, ONE barrier per step, 2-step
// register prefetch of child inputs, f16 results + f16 emb table.
//
// ws: resultsH f16[12500*128] | wfrag f16[131072] | bias4 float4[128]
//     | embH f16[131*128]

#define D 128
#define NTOT 100000
#define NINT 12500
#define NTYPES 131

typedef _Float16 f16x8 __attribute__((ext_vector_type(8)));
typedef _Float16 f16x4 __attribute__((ext_vector_type(4)));
typedef float    f32x4 __attribute__((ext_vector_type(4)));

__device__ __forceinline__ float fsig(float x) {
    return __builtin_amdgcn_rcpf(1.f + __expf(-x));
}
__device__ __forceinline__ float ftanh(float x) {
    return 1.f - 2.f * __builtin_amdgcn_rcpf(__expf(2.f * x) + 1.f);
}

// MFMA with B pinned to AGPRs: compiler cannot rematerialize/spill asm operands.
#define MFMA_AB(ACC, A, B) \
    asm("v_mfma_f32_16x16x32_f16 %0, %1, %2, %0" : "+v"(ACC) : "v"(A), "a"(B))

template<int DPT> struct XVT;
template<> struct XVT<8> { using T = f16x8; };
template<> struct XVT<4> { using T = f16x4; };

// Pack weights into per-(wave,gate,ktile,lane) f16 B-fragments, fuse biases,
// convert embedding table to f16.
//   frag half index (((w*4+ct)*8+kk)*64 + l)*8 + j  holds  Wcat[k][c]:
//     k = (kk&3)*32 + (l>>4)*8 + j, src = kk<4 ? W_ih : W_hh
//     c = ct*128 + w*16 + (l&15);  B[k][c] = W[c][k]
__global__ void prep(const float* __restrict__ W_ih, const float* __restrict__ W_hh,
                     const float* __restrict__ b_ih, const float* __restrict__ b_hh,
                     const float* __restrict__ emb,
                     _Float16* __restrict__ wfrag, float4* __restrict__ bias4,
                     _Float16* __restrict__ embH)
{
    int t = blockIdx.x * blockDim.x + threadIdx.x;   // 16896 threads
    if (t < 8 * 4 * 8 * 64) {
        int l  = t & 63;
        int kk = (t >> 6) & 7;
        int ct = (t >> 9) & 3;
        int w  = (t >> 11) & 7;
        int k0 = (kk & 3) * 32 + ((l >> 4) * 8);
        int c  = ct * 128 + w * 16 + (l & 15);
        const float* src = (kk < 4) ? (W_ih + (size_t)c * D + k0)
                                    : (W_hh + (size_t)c * D + k0);
        f16x8 v;
#pragma unroll
        for (int j = 0; j < 8; ++j) v[j] = (_Float16)src[j];
        *(f16x8*)(wfrag + (size_t)t * 8) = v;
    }
    if (t < D) {
        bias4[t] = make_float4(b_ih[t      ] + b_hh[t      ],
                               b_ih[t + 128] + b_hh[t + 128],
                               b_ih[t + 256] + b_hh[t + 256],
                               b_ih[t + 384] + b_hh[t + 384]);
    }
    if (t < NTYPES * D / 8) {
        f16x8 v;
#pragma unroll
        for (int j = 0; j < 8; ++j) v[j] = (_Float16)emb[t * 8 + j];
        *(f16x8*)(embH + (size_t)t * 8) = v;
    }
}

template<int RT, bool FUSE_ROOT>
__global__ __launch_bounds__(512) void lstm_level(
    int start, int count,
    const _Float16* __restrict__ embH, const int* __restrict__ node_types,
    const int* __restrict__ children,
    const _Float16* __restrict__ wfrag, const float4* __restrict__ bias4,
    _Float16* __restrict__ resultsH, float* __restrict__ out)
{
    constexpr int NR  = 16 * RT;
    constexpr int TPR = 512 / NR;
    constexpr int DPT = 128 / TPR;
    using xvec = typename XVT<DPT>::T;

    __shared__ __align__(16) _Float16 Xh[2][NR][264];   // [buf][node][ x(128)|h(128)|pad ]
    __shared__ int chid_s[NR][8];
    __shared__ int chty_s[NR][8];
    __shared__ __align__(16) _Float16 Hstash[8][128];

    const int t  = threadIdx.x;
    const int w  = t >> 6;
    const int l  = t & 63;
    const int n0 = start + (int)blockIdx.x * NR;
    const int B  = min(NR, start + count - n0);

    const int row  = t / TPR;
    const int di   = (t % TPR) * DPT;
    const int dcol = w * 16 + (l & 15);

    // ---- stage child ids + leaf-child types ----
    if (t < NR * 8) {
        int rr = t >> 3, slot = t & 7;
        int ch = children[(size_t)(n0 + rr) * 8 + slot];
        chid_s[rr][slot] = ch;
        chty_s[rr][slot] = (ch >= NINT && ch < NTOT) ? node_types[ch] : 0;
    }

    // ---- weights: 32 clean 16B loads -> AGPR-pinned B-fragments ----
    f16x8 bf[4][8];
#pragma unroll
    for (int ct = 0; ct < 4; ++ct)
#pragma unroll
        for (int kk = 0; kk < 8; ++kk)
            bf[ct][kk] = *(const f16x8*)(wfrag + ((size_t)(((w * 4 + ct) * 8 + kk) * 64 + l)) * 8);
    const float4 bb = bias4[dcol];

    __syncthreads();   // chid_s/chty_s visible

    auto issue_gather = [&](int s) -> xvec {
        const _Float16* src;
        if (s == 0) {
            src = embH + (size_t)node_types[n0 + row] * D + di;
        } else {
            int ch = chid_s[row][s - 1];
            if (ch >= NTOT) return (xvec)(_Float16)0.f;
            src = (ch < NINT) ? (resultsH + (size_t)ch * D + di)
                              : (embH + (size_t)chty_s[row][s - 1] * D + di);
        }
        return *(const xvec*)src;
    };

    // ---- prologue: x0 + zero h into buf0; prefetch x1,x2 ----
    *(xvec*)&Xh[0][row][di]       = issue_gather(0);
    *(xvec*)&Xh[0][row][128 + di] = (xvec)(_Float16)0.f;
    xvec xA = issue_gather(1);
    xvec xB = issue_gather(2);

    float cr[RT][4], hr[RT][4];
#pragma unroll
    for (int rt = 0; rt < RT; ++rt)
#pragma unroll
        for (int r = 0; r < 4; ++r) { cr[rt][r] = 0.f; hr[rt][r] = 0.f; }

    f32x4 acc[RT][4];
    auto mfma_phase = [&](int b) {
#pragma unroll
        for (int rt = 0; rt < RT; ++rt)
#pragma unroll
            for (int ct = 0; ct < 4; ++ct) acc[rt][ct] = (f32x4){0.f, 0.f, 0.f, 0.f};
#pragma unroll
        for (int kk = 0; kk < 8; ++kk) {
#pragma unroll
            for (int rt = 0; rt < RT; ++rt) {
                f16x8 a = *(const f16x8*)&Xh[b][rt * 16 + (l & 15)][kk * 32 + ((l >> 4) * 8)];
#pragma unroll
                for (int ct = 0; ct < 4; ++ct)
                    MFMA_AB(acc[rt][ct], a, bf[ct][kk]);
            }
        }
    };
    auto cell_phase = [&](int s, int b, bool always) {
#pragma unroll
        for (int rt = 0; rt < RT; ++rt)
#pragma unroll
            for (int r = 0; r < 4; ++r) {
                const int r2 = rt * 16 + ((l >> 4) * 4) + r;
                const bool upd = always || (s == 0) || (chid_s[r2][s - 1] < NTOT);
                if (upd) {
                    float iv = fsig (acc[rt][0][r] + bb.x);
                    float fv = fsig (acc[rt][1][r] + bb.y);
                    float gv = ftanh(acc[rt][2][r] + bb.z);
                    float ov = fsig (acc[rt][3][r] + bb.w);
                    float cn = fv * cr[rt][r] + iv * gv;
                    cr[rt][r] = cn;
                    hr[rt][r] = ov * ftanh(cn);
                }
                if (s < 8) Xh[b ^ 1][r2][128 + dcol] = (_Float16)hr[rt][r];
            }
    };

    __syncthreads();   // buf0 ready

    for (int s = 0; s < 9; ++s) {
        const int b = s & 1;
        mfma_phase(b);
        if (s < 8) {
            *(xvec*)&Xh[b ^ 1][row][di] = xA;
            xA = xB;
            if (s <= 5) xB = issue_gather(s + 3);
        }
        cell_phase(s, b, false);
        __syncthreads();
    }

    // ---- epilogue ----
#pragma unroll
    for (int rt = 0; rt < RT; ++rt)
#pragma unroll
        for (int r = 0; r < 4; ++r) {
            const int r2 = rt * 16 + ((l >> 4) * 4) + r;
            if (r2 < B) {
                resultsH[(size_t)(n0 + r2) * D + dcol] = (_Float16)hr[rt][r];
                if (FUSE_ROOT && r2 < 8) Hstash[r2][dcol] = (_Float16)hr[rt][r];
            }
        }

    // ---- fused root pass: node 0, children 1..8 live in Hstash ----
    if constexpr (FUSE_ROOT) {
        __syncthreads();
        *(xvec*)&Xh[0][row][di]       = *(const xvec*)(embH + (size_t)node_types[0] * D + di);
        *(xvec*)&Xh[0][row][128 + di] = (xvec)(_Float16)0.f;
#pragma unroll
        for (int rt = 0; rt < RT; ++rt)
#pragma unroll
            for (int r = 0; r < 4; ++r) { cr[rt][r] = 0.f; hr[rt][r] = 0.f; }
        __syncthreads();

        for (int s = 0; s < 9; ++s) {
            const int b = s & 1;
            mfma_phase(b);
            if (s < 8)
                *(xvec*)&Xh[b ^ 1][row][di] = *(const xvec*)&Hstash[s][di];
            cell_phase(s, b, true);
            __syncthreads();
        }
        if ((l >> 4) == 0) out[dcol] = hr[0][0];
    }
}

extern "C" void kernel_launch(void* const* d_in, const int* in_sizes, int n_in,
                              void* d_out, int out_size, void* d_ws, size_t ws_size,
                              hipStream_t stream)
{
    const float* emb        = (const float*)d_in[0];
    const float* W_ih       = (const float*)d_in[1];
    const float* W_hh       = (const float*)d_in[2];
    const float* b_ih       = (const float*)d_in[3];
    const float* b_hh       = (const float*)d_in[4];
    const int*   node_types = (const int*)d_in[5];
    const int*   children   = (const int*)d_in[6];

    float* out = (float*)d_out;

    char*      ws       = (char*)d_ws;
    _Float16*  resultsH = (_Float16*)ws;                        // 3,200,000 B
    size_t     off      = ((size_t)NINT * D * 2 + 255) & ~(size_t)255;
    _Float16*  wfrag    = (_Float16*)(ws + off);                // 262,144 B
    float4*    bias4    = (float4*)(ws + off + 262144);         // 2,048 B
    _Float16*  embH     = (_Float16*)(ws + off + 262144 + 2048); // 33,536 B

    prep<<<66, 256, 0, stream>>>(W_ih, W_hh, b_ih, b_hh, emb, wfrag, bias4, embH);

    lstm_level<2,false><<<245, 512, 0, stream>>>(4681, 7819, embH, node_types, children,
                                                 wfrag, bias4, resultsH, out);
    lstm_level<1,false><<<256, 512, 0, stream>>>(585, 4096, embH, node_types, children,
                                                 wfrag, bias4, resultsH, out);
    lstm_level<1,false><<<32, 512, 0, stream>>>(73, 512, embH, node_types, children,
                                                wfrag, bias4, resultsH, out);
    lstm_level<1,false><<<4, 512, 0, stream>>>(9, 64, embH, node_types, children,
                                               wfrag, bias4, resultsH, out);
    lstm_level<1,true><<<1, 512, 0, stream>>>(1, 8, embH, node_types, children,
                                              wfrag, bias4, resultsH, out);
}